// Round 9
// baseline (591.052 us; speedup 1.0000x reference)
//
#include <hip/hip_runtime.h>
#include <hip/hip_bf16.h>
#include <math.h>

// Problem constants
#define Bb 2
#define Nn 2048
#define Dd 512
#define Hh 8
#define Ll 4
#define Kk 32
#define Vv 256
#define HDh 64
#define Mrows (Bb*Nn)   // 4096

static constexpr float SCALE_QK = 0.125f;           // 1/sqrt(64)
static constexpr float INV_MOD = 1.0f / 4294967296.0f;

typedef _Float16 f16;
typedef _Float16 f16x8 __attribute__((ext_vector_type(8)));
typedef _Float16 f16x4 __attribute__((ext_vector_type(4)));
typedef _Float16 f16x2 __attribute__((ext_vector_type(2)));
typedef float f32x4 __attribute__((ext_vector_type(4)));
typedef unsigned long long u64;

// ---- async global->LDS, 16B per lane (dest must be linear: base+lane*16) ---
#define AS_GLOBAL(p) ((const __attribute__((address_space(1))) void*)(p))
#define AS_LDS(p)    ((__attribute__((address_space(3))) void*)(p))
__device__ __forceinline__ void gload16(const f16* g, f16* l) {
    __builtin_amdgcn_global_load_lds(AS_GLOBAL(g), AS_LDS(l), 16, 0, 0);
}

// ------- fused tiny prep: scal + bias concat + emb f32->f16 -----------------
__global__ __launch_bounds__(256)
void prep_kernel(const float* __restrict__ log_c, const float* __restrict__ log_tau,
                 float* __restrict__ scal,
                 const float* __restrict__ bq, const float* __restrict__ bk,
                 const float* __restrict__ bv, float* __restrict__ bqkv,
                 const float* __restrict__ emb, f16* __restrict__ emb16) {
    int id = blockIdx.x * 256 + threadIdx.x;     // 512 blocks x 256 = 131072
    if (id < Vv * Dd) emb16[id] = (f16)emb[id];
    if (id < Ll * 1536) {
        int l = id / 1536, r = id % 1536;
        const float* src = (r < 512) ? bq : ((r < 1024) ? bk : bv);
        bqkv[id] = src[l * 512 + (r & 511)];
    }
    if (id == 0) {
        float c = expf(log_c[0]);
        scal[0] = c;
        scal[1] = sqrtf(c);
    }
    if (id < Ll) scal[2 + id] = 1.0f / (expf(log_tau[id]) + 1e-8f);
}

// ------- hvec split-K GEMV, coalesced: part[b][n] = sum_{kx in slice} -------
__global__ __launch_bounds__(256)
void hvec_part_kernel(const float* __restrict__ hash_proj,
                      const float* __restrict__ Wb,
                      float* __restrict__ part) {
    const int b = blockIdx.x;            // 32 blocks, 16 k-rows each
    const int t = threadIdx.x;
    float a0 = 0.f, a1 = 0.f;
#pragma unroll
    for (int i = 0; i < 16; i++) {
        int kx = b * 16 + i;
        float hp = hash_proj[kx];
        const float* wr = Wb + (size_t)(Dd + kx) * Dd;
        a0 = fmaf(hp, wr[t], a0);
        a1 = fmaf(hp, wr[t + 256], a1);
    }
    part[b * Dd + t]       = a0;
    part[b * Dd + t + 256] = a1;
}
__global__ __launch_bounds__(256)
void hvec_red_kernel(const float* __restrict__ part, float* __restrict__ hvec) {
    const int n = blockIdx.x * 256 + threadIdx.x;   // 2 blocks
    float acc = 0.f;
#pragma unroll
    for (int b = 0; b < 32; b++) acc += part[b * Dd + n];
    hvec[n] = acc;
}

// ---------------- convert + transpose: W (K x N f32) -> Wt (N x K f16) ------
__global__ __launch_bounds__(256)
void trans_kernel(const float* __restrict__ src, f16* __restrict__ dst,
                  int K, int N, long sStride, long dStride) {
    __shared__ float tile[32][33];
    const float* s = src + blockIdx.z * sStride;
    f16* d = dst + blockIdx.z * dStride;
    int k0 = blockIdx.y * 32, n0 = blockIdx.x * 32;
    int tx = threadIdx.x & 31, ty = threadIdx.x >> 5;   // ty 0..7
#pragma unroll
    for (int i = 0; i < 32; i += 8)
        tile[ty + i][tx] = s[(long)(k0 + ty + i) * N + n0 + tx];
    __syncthreads();
#pragma unroll
    for (int i = 0; i < 32; i += 8)
        d[(long)(n0 + ty + i) * K + k0 + tx] = (f16)tile[tx][ty + i];
}

// ---- merged transpose for the four 512x512 weight families (z = w*4 + l) ---
__global__ __launch_bounds__(256)
void trans4_kernel(const float* __restrict__ Wq, const float* __restrict__ Wk,
                   const float* __restrict__ Wv, const float* __restrict__ Wo,
                   f16* __restrict__ Wqkvt, f16* __restrict__ Wot) {
    __shared__ float tile[32][33];
    const int which = blockIdx.z >> 2, l = blockIdx.z & 3;
    const float* s;
    f16* d;
    switch (which) {
        case 0: s = Wq + (size_t)l * 262144; d = Wqkvt + (size_t)l * 786432;          break;
        case 1: s = Wk + (size_t)l * 262144; d = Wqkvt + (size_t)l * 786432 + 262144; break;
        case 2: s = Wv + (size_t)l * 262144; d = Wqkvt + (size_t)l * 786432 + 524288; break;
        default:s = Wo + (size_t)l * 262144; d = Wot   + (size_t)l * 262144;          break;
    }
    int k0 = blockIdx.y * 32, n0 = blockIdx.x * 32;
    int tx = threadIdx.x & 31, ty = threadIdx.x >> 5;
#pragma unroll
    for (int i = 0; i < 32; i += 8)
        tile[ty + i][tx] = s[(long)(k0 + ty + i) * 512 + n0 + tx];
    __syncthreads();
#pragma unroll
    for (int i = 0; i < 32; i += 8)
        d[(long)(n0 + ty + i) * 512 + k0 + tx] = (f16)tile[tx][ty + i];
}

// ---------------- MFMA f16 GEMM: C = op(A @ Wt^T + bias), BK=64 -------------
// R9: GEMMs here are STAGING-BW-bound (staged bytes = N/TN*A + M/TM*B >> MFMA
// time), so bigger tiles cut traffic: W2 -> 128x64 (384->192 MB staged, grid
// 256 = 1 block/CU, depth-2 keeps the load queue full); W1 -> 128x128
// (192->128 MB, 512 = 2 blocks/CU exact). Wave map generalized: WRN x WCN
// waves, each WRE x COLE output, acc[NIT][NJT]. TN=64: 3 LDS buffers,
// depth-2 prefetch, counted vmcnt(NCHT). TN=128: 2-buffer, exact vmcnt(0).
// LDS dest linear; XOR bank-swizzle folded into pre-swizzled GLOBAL source.
template<int TM, int TN, bool GATHER, bool RANK1, bool GELU, bool RES, bool OUT16>
__global__ __launch_bounds__(256)
void mgemm(const f16* __restrict__ A, const f16* __restrict__ Wt,
           const float* __restrict__ bias,
           const int* __restrict__ gidx,
           const int* __restrict__ hashes, const float* __restrict__ hvec,
           const float* __restrict__ resid,
           void* __restrict__ Cout, int M, int N, int K) {
    constexpr int WRN = (TN == 64) ? 2 : ((TM == 128) ? 2 : 1);
    constexpr int WCN = 4 / WRN;              // wave-grid cols
    constexpr int WRE = TM / WRN;             // wave row extent (16/32/64)
    constexpr int NIT = WRE / 16;             // row tiles/wave (1/2/4)
    constexpr int COLE = TN / WCN;            // wave col extent (32 or 64)
    constexpr int NJT = COLE / 16;            // col tiles/wave (2 or 4)
    constexpr int ACH = TM * 8;               // A chunks (16B), BK=64 f16 = 8/row
    constexpr int BCH = TN * 8;
    constexpr int NCH = ACH + BCH;
    constexpr int NCHT = NCH / 256;           // 3,4,6,8
    constexpr int NBUF = (TN == 64) ? 3 : 2;
    static_assert(NCH % 256 == 0, "chunk count must tile the block");
    __shared__ __align__(16) f16 sm[NBUF][NCH * 8];
    const int t = threadIdx.x;
    const int lane = t & 63;
    const int w = t >> 6;
    const int wr = w / WCN, wc = w % WCN;
    const int i0 = blockIdx.y * TM, j0 = blockIdx.x * TN;

    const f16* gsrc[NCHT];
#pragma unroll
    for (int q = 0; q < NCHT; q++) {
        int c = t + q * 256;
        if (c < ACH) {
            int m = c >> 3, kb = (c & 7) ^ (m & 7);
            long row = GATHER ? (long)gidx[i0 + m] : (long)(i0 + m);
            gsrc[q] = A + row * K + kb * 8;
        } else {
            int cc = c - ACH;
            int n = cc >> 3, kb = (cc & 7) ^ (n & 7);
            gsrc[q] = Wt + (long)(j0 + n) * K + kb * 8;
        }
    }

    f32x4 acc[NIT][NJT];
#pragma unroll
    for (int i = 0; i < NIT; i++)
#pragma unroll
        for (int j = 0; j < NJT; j++) acc[i][j] = (f32x4){0.f, 0.f, 0.f, 0.f};

    auto compute = [&](const f16* rbuf) {
#pragma unroll
        for (int kh = 0; kh < 2; kh++) {
            f16x8 af[NIT], bf[NJT];
#pragma unroll
            for (int i = 0; i < NIT; i++) {
                int m = wr * WRE + i * 16 + (lane & 15);
                int sl = m * 8 + ((kh * 4 + (lane >> 4)) ^ (m & 7));
                af[i] = *(const f16x8*)(rbuf + sl * 8);
            }
#pragma unroll
            for (int j = 0; j < NJT; j++) {
                int n = wc * COLE + j * 16 + (lane & 15);
                int sl = ACH + n * 8 + ((kh * 4 + (lane >> 4)) ^ (n & 7));
                bf[j] = *(const f16x8*)(rbuf + sl * 8);
            }
#pragma unroll
            for (int i = 0; i < NIT; i++)
#pragma unroll
                for (int j = 0; j < NJT; j++)
                    acc[i][j] = __builtin_amdgcn_mfma_f32_16x16x32_f16(af[i], bf[j], acc[i][j], 0, 0, 0);
        }
    };

    if constexpr (TN == 64) {
        static_assert(NCHT == 3 || NCHT == 4 || NCHT == 6, "vmcnt immediate coverage");
        const int T = K >> 6;
        // prologue: sets 0 and 1
#pragma unroll
        for (int q = 0; q < NCHT; q++) gload16(gsrc[q],      &sm[0][(t + q * 256) * 8]);
#pragma unroll
        for (int q = 0; q < NCHT; q++) gload16(gsrc[q] + 64, &sm[1][(t + q * 256) * 8]);
        f16 *bA = sm[0], *bB = sm[1], *bC = sm[2];
        for (int tt = 0; tt < T - 1; ++tt) {
            // set tt landed; set tt+1 (NCHT loads) stays in flight
            if constexpr (NCHT == 3)      asm volatile("s_waitcnt vmcnt(3)" ::: "memory");
            else if constexpr (NCHT == 4) asm volatile("s_waitcnt vmcnt(4)" ::: "memory");
            else                          asm volatile("s_waitcnt vmcnt(6)" ::: "memory");
            __syncthreads();
            if (tt + 2 < T) {
                const int kt2 = (tt + 2) << 6;
#pragma unroll
                for (int q = 0; q < NCHT; q++)
                    gload16(gsrc[q] + kt2, bC + (t + q * 256) * 8);
            }
            compute(bA);
            f16* tmp = bA; bA = bB; bB = bC; bC = tmp;
        }
        asm volatile("s_waitcnt vmcnt(0)" ::: "memory");
        __syncthreads();
        compute(bA);
    } else {
        // 2-buffer, exact vmcnt(0) (single set in flight at the wait)
#pragma unroll
        for (int q = 0; q < NCHT; q++)
            gload16(gsrc[q], &sm[0][(t + q * 256) * 8]);
        auto step = [&](int kt, const f16* rbuf, f16* wbuf) {
            asm volatile("s_waitcnt vmcnt(0)" ::: "memory");
            __syncthreads();                  // rbuf staged + wbuf reads done
            if (kt + 64 < K) {
#pragma unroll
                for (int q = 0; q < NCHT; q++)
                    gload16(gsrc[q] + kt + 64, wbuf + (t + q * 256) * 8);
            }
            compute(rbuf);
        };
        for (int kt = 0; kt < K; kt += 128) { // K/64 even at all call sites
            step(kt,      sm[0], sm[1]);
            step(kt + 64, sm[1], sm[0]);
        }
    }

    // epilogue: C/D layout col=lane&15, row=(lane>>4)*4+v
    float* Cf = (float*)Cout;
    f16*   Ch = (f16*)Cout;
#pragma unroll
    for (int i = 0; i < NIT; i++) {
        int rbase = i0 + wr * WRE + i * 16 + ((lane >> 4) << 2);
#pragma unroll
        for (int v = 0; v < 4; v++) {
            int row = rbase + v;
            float hterm = RANK1 ? (float)hashes[row] * INV_MOD : 0.f;
#pragma unroll
            for (int j = 0; j < NJT; j++) {
                int col = j0 + wc * COLE + j * 16 + (lane & 15);
                float val = acc[i][j][v] + bias[col];
                if (RANK1) val += hterm * hvec[col];
                if (GELU)  val = 0.5f * val * (1.f + erff(val * 0.7071067811865475f));
                if (RES)   val += resid[(long)row * N + col];
                if (OUT16) Ch[(long)row * N + col] = (f16)val;
                else       Cf[(long)row * N + col] = val;
            }
        }
    }
}

// ---------------- MFMA Poincare "arg" matrix (BK=64, TM=TN=64) --------------
// poshl: 2048 x 1024 f16, row = [hi(512) | lo(512)], pos ~= hi+lo (22-bit).
// Writes arg = max(1 + 2c*d2/denom, 1) — MONOTONE in dist, top-k on arg ==
// top-k on dist; acosh deferred to winners (topk_kernel).
// R9: arg(i,j) is BIT-IDENTICAL to arg(j,i) (products commute, same MFMA
// reduce order), so only the 528 upper-triangle tiles are computed; the
// mirror tile is written via an LDS-transposed coalesced pass. -48% MFMA
// and fetch, zero numerics change.
__global__ __launch_bounds__(256)
void mdist_kernel(const f16* __restrict__ poshl, const float* __restrict__ xx,
                  const float* __restrict__ scal, float* __restrict__ dist) {
    constexpr int TM = 64, TN = 64;
    constexpr int ACH = TM * 8, BCH = TN * 8, NCH = ACH + BCH;   // 1024
    constexpr int NCHT = NCH / 256;                               // 4
    constexpr int KK = 1024;
    __shared__ __align__(16) f16 sm[3][NCH * 8];
    const int t = threadIdx.x;
    const int lane = t & 63;
    const int w = t >> 6;
    const int wr = w >> 1, wc = w & 1;

    // triangular decode: bi -> (by, bx), by <= bx; S(r) = 32r - r(r-1)/2
    const int bi = blockIdx.x;
    int r = (int)((65.0f - sqrtf(4225.0f - 8.0f * (float)bi)) * 0.5f);
    while (32 * (r + 1) - ((r + 1) * r) / 2 <= bi) r++;
    while (32 * r - (r * (r - 1)) / 2 > bi) r--;
    const int by = r, bx = r + (bi - (32 * r - (r * (r - 1)) / 2));
    const int i0 = by * TM, j0 = bx * TN;

    const f16* gsrc[NCHT];
#pragma unroll
    for (int q = 0; q < NCHT; q++) {
        int c = t + q * 256;
        if (c < ACH) {
            int m = c >> 3, kb = (c & 7) ^ (m & 7);
            gsrc[q] = poshl + (long)(i0 + m) * KK + kb * 8;
        } else {
            int cc = c - ACH;
            int n = cc >> 3, kb = (cc & 7) ^ (n & 7);
            gsrc[q] = poshl + (long)(j0 + n) * KK + kb * 8;
        }
    }

    f32x4 acc[2][2];
#pragma unroll
    for (int i = 0; i < 2; i++)
#pragma unroll
        for (int j = 0; j < 2; j++) acc[i][j] = (f32x4){0.f, 0.f, 0.f, 0.f};

    auto compute = [&](const f16* rbuf) {
#pragma unroll
        for (int kh = 0; kh < 2; kh++) {
            f16x8 af[2], bf[2];
#pragma unroll
            for (int i = 0; i < 2; i++) {
                int m = wr * 32 + i * 16 + (lane & 15);
                int sl = m * 8 + ((kh * 4 + (lane >> 4)) ^ (m & 7));
                af[i] = *(const f16x8*)(rbuf + sl * 8);
            }
#pragma unroll
            for (int j = 0; j < 2; j++) {
                int n = wc * 32 + j * 16 + (lane & 15);
                int sl = ACH + n * 8 + ((kh * 4 + (lane >> 4)) ^ (n & 7));
                bf[j] = *(const f16x8*)(rbuf + sl * 8);
            }
#pragma unroll
            for (int i = 0; i < 2; i++)
#pragma unroll
                for (int j = 0; j < 2; j++)
                    acc[i][j] = __builtin_amdgcn_mfma_f32_16x16x32_f16(af[i], bf[j], acc[i][j], 0, 0, 0);
        }
    };

#pragma unroll
    for (int q = 0; q < NCHT; q++) gload16(gsrc[q],      &sm[0][(t + q * 256) * 8]);
#pragma unroll
    for (int q = 0; q < NCHT; q++) gload16(gsrc[q] + 64, &sm[1][(t + q * 256) * 8]);
    f16 *bA = sm[0], *bB = sm[1], *bC = sm[2];
    constexpr int T = KK >> 6;                // 16
    for (int tt = 0; tt < T - 1; ++tt) {
        asm volatile("s_waitcnt vmcnt(4)" ::: "memory");
        __syncthreads();
        if (tt + 2 < T) {
            const int kt2 = (tt + 2) << 6;
#pragma unroll
            for (int q = 0; q < NCHT; q++)
                gload16(gsrc[q] + kt2, bC + (t + q * 256) * 8);
        }
        compute(bA);
        f16* tmp = bA; bA = bB; bB = bC; bC = tmp;
    }
    asm volatile("s_waitcnt vmcnt(0)" ::: "memory");
    __syncthreads();
    compute(bA);

    // epilogue: compute args into regs, write direct tile; mirror via LDS
    const float c = scal[0];
    float vals[2][4][2];
#pragma unroll
    for (int i = 0; i < 2; i++) {
        int rbase = i0 + wr * 32 + i * 16 + ((lane >> 4) << 2);
#pragma unroll
        for (int v = 0; v < 4; v++) {
            int row = rbase + v;
            float xi = xx[row];
#pragma unroll
            for (int j = 0; j < 2; j++) {
                int col = j0 + wc * 32 + j * 16 + (lane & 15);
                float xj = xx[col];
                float d2 = fmaxf(xi + xj - 2.f * acc[i][j][v], 0.f);
                float denom = (1.f - c * xi) * (1.f - c * xj) + 1e-8f;
                float arg = fmaxf(1.f + 2.f * c * d2 / denom, 1.f);
                vals[i][v][j] = arg;
                dist[(long)row * Nn + col] = arg;
            }
        }
    }
    if (bx != by) {
        __syncthreads();                      // all compute reads of sm done
        float* trf = (float*)sm;              // [64][65] padded transpose tile
#pragma unroll
        for (int i = 0; i < 2; i++) {
#pragma unroll
            for (int v = 0; v < 4; v++) {
                int rw = wr * 32 + i * 16 + ((lane >> 4) << 2) + v;
#pragma unroll
                for (int j = 0; j < 2; j++) {
                    int cl = wc * 32 + j * 16 + (lane & 15);
                    trf[cl * 65 + rw] = vals[i][v][j];
                }
            }
        }
        __syncthreads();
        const int cl = t >> 2, q4 = t & 3;
#pragma unroll
        for (int s = 0; s < 4; s++) {
            int rw = q4 * 16 + s * 4;
            float4 wv;
            wv.x = trf[cl * 65 + rw];
            wv.y = trf[cl * 65 + rw + 1];
            wv.z = trf[cl * 65 + rw + 2];
            wv.w = trf[cl * 65 + rw + 3];
            *(float4*)(dist + (long)(j0 + cl) * Nn + i0 + rw) = wv;
        }
    }
}

// ---------------- LayerNorm (512): 4 rows/block, 1 wave/row, float4 ---------
__global__ __launch_bounds__(256)
void ln_kernel(const float* __restrict__ x, const float* __restrict__ g,
               const float* __restrict__ be, f16* __restrict__ xn) {
    const int row = blockIdx.x * 4 + (threadIdx.x >> 6);
    const int t = threadIdx.x & 63;
    const float4* xr = (const float4*)(x + (size_t)row * Dd);
    float4 v0 = xr[t], v1 = xr[t + 64];
    float s = v0.x + v0.y + v0.z + v0.w + v1.x + v1.y + v1.z + v1.w;
#pragma unroll
    for (int off = 32; off; off >>= 1) s += __shfl_xor(s, off, 64);
    float mean = s * (1.f / Dd);
    float d0x = v0.x - mean, d0y = v0.y - mean, d0z = v0.z - mean, d0w = v0.w - mean;
    float d1x = v1.x - mean, d1y = v1.y - mean, d1z = v1.z - mean, d1w = v1.w - mean;
    float q = d0x*d0x + d0y*d0y + d0z*d0z + d0w*d0w
            + d1x*d1x + d1y*d1y + d1z*d1z + d1w*d1w;
#pragma unroll
    for (int off = 32; off; off >>= 1) q += __shfl_xor(q, off, 64);
    float rstd = rsqrtf(q * (1.f / Dd) + 1e-5f);
    float4 g0 = ((const float4*)g)[t], g1v = ((const float4*)g)[t + 64];
    float4 b0 = ((const float4*)be)[t], b1v = ((const float4*)be)[t + 64];
    f16* xo = xn + (size_t)row * Dd;
    f16x4 o0, o1;
    o0[0] = (f16)(d0x * rstd * g0.x + b0.x);
    o0[1] = (f16)(d0y * rstd * g0.y + b0.y);
    o0[2] = (f16)(d0z * rstd * g0.z + b0.z);
    o0[3] = (f16)(d0w * rstd * g0.w + b0.w);
    o1[0] = (f16)(d1x * rstd * g1v.x + b1v.x);
    o1[1] = (f16)(d1y * rstd * g1v.y + b1v.y);
    o1[2] = (f16)(d1z * rstd * g1v.z + b1v.z);
    o1[3] = (f16)(d1w * rstd * g1v.w + b1v.w);
    *(f16x4*)(xo + t * 4)         = o0;
    *(f16x4*)(xo + (t + 64) * 4)  = o1;
}

// ---------------- expmap0 -> poshl (f16 hi|lo), xx = |pos|^2 (f32) ----------
__global__ __launch_bounds__(256)
void expmap_kernel(const float* __restrict__ vt, const float* __restrict__ scal,
                   f16* __restrict__ poshl, float* __restrict__ xx) {
    __shared__ float red[256];
    const int row = blockIdx.x, t = threadIdx.x;
    const float* vr = vt + (size_t)row * Dd;
    float v0 = vr[t], v1 = vr[t + 256];
    red[t] = v0 * v0 + v1 * v1;
    __syncthreads();
    for (int off = 128; off; off >>= 1) {
        if (t < off) red[t] += red[t + off];
        __syncthreads();
    }
    float total = red[0];
    float vn = fmaxf(sqrtf(total), 1e-8f);
    float sc = scal[1];
    float factor = tanhf(sc * vn) / (sc * vn);
    float p0 = factor * v0, p1 = factor * v1;
    f16 h0 = (f16)p0, h1 = (f16)p1;
    f16* pr = poshl + (size_t)row * 1024;
    pr[t]             = h0;
    pr[t + 256]       = h1;
    pr[512 + t]       = (f16)(p0 - (float)h0);
    pr[512 + t + 256] = (f16)(p1 - (float)h1);
    if (t == 0) xx[row] = factor * factor * total;
}

// ---------------- top-K=32: bisection threshold + rank-select ---------------
__global__ __launch_bounds__(256)
void topk_kernel(const float* __restrict__ dist, const float* __restrict__ scal,
                 float* __restrict__ outd, int* __restrict__ outi) {
    __shared__ unsigned wred[4];
    __shared__ unsigned bc;
    __shared__ __align__(8) u64 buf[128];
    const int t = threadIdx.x;
    const int w = t >> 6;
    const int n = blockIdx.x;
    const float sqc = scal[1];
    const uint4* dr = (const uint4*)(dist + (size_t)n * Nn);

    uint4 va = dr[t * 2];
    uint4 vb = dr[t * 2 + 1];
    unsigned k[8] = {va.x, va.y, va.z, va.w, vb.x, vb.y, vb.z, vb.w};
    const int g0 = t * 8;

    // ---- bisection: find hi with 32 <= cnt(v < hi) <= 96 (or hi-lo==1) ----
    unsigned lo = 0x3F800000u;   // 1.0f bits: cnt(v<1.0)==0 (args >= 1)
    unsigned hi = 0x7F800001u;   // above +inf bits: counts all 2048
    unsigned chi = 2048u;
    while (chi > 96u && (hi - lo) > 1u) {
        unsigned mid = lo + ((hi - lo) >> 1);
        int c = 0;
#pragma unroll
        for (int j = 0; j < 8; j++) c += (k[j] < mid) ? 1 : 0;
#pragma unroll
        for (int off = 32; off; off >>= 1) c += __shfl_xor(c, off, 64);
        __syncthreads();                     // protect wred reads of prev iter
        if ((t & 63) == 0) wred[w] = (unsigned)c;
        __syncthreads();
        unsigned ct = wred[0] + wred[1] + wred[2] + wred[3];
        if (ct >= 32u) { hi = mid; chi = ct; } else { lo = mid; }
    }

    if (chi <= 96u) {
        // ---- normal path: compact candidates, rank-select ----
        if (t == 0) bc = 0u;
        __syncthreads();
#pragma unroll
        for (int j = 0; j < 8; j++) {
            if (k[j] < hi) {
                unsigned s = atomicAdd(&bc, 1u);
                buf[s] = ((u64)k[j] << 11) | (u64)(unsigned)(g0 + j);
            }
        }
        __syncthreads();
        const int m = (int)chi;
        if (t < m) {
            u64 my = buf[t];
            int r = 0;
            for (int j = 0; j < m; j++) r += (buf[j] < my) ? 1 : 0;
            if (r < Kk) {
                float v = __uint_as_float((unsigned)(my >> 11));
                outd[n * Kk + r] = acoshf(v) / sqc;
                outi[n * Kk + r] = (int)(my & 2047u);
            }
        }
    } else {
        // ---- exhaustion path: hi == lo+1; {v<hi} = {v<lo} U {v==lo} ----
        int c = 0;
#pragma unroll
        for (int j = 0; j < 8; j++) c += (k[j] < lo) ? 1 : 0;
#pragma unroll
        for (int off = 32; off; off >>= 1) c += __shfl_xor(c, off, 64);
        __syncthreads();
        if ((t & 63) == 0) wred[w] = (unsigned)c;
        if (t == 0) bc = 0u;
        __syncthreads();
        const int cless = (int)(wred[0] + wred[1] + wred[2] + wred[3]);
#pragma unroll
        for (int j = 0; j < 8; j++) {
            if (k[j] < lo) {
                unsigned s = atomicAdd(&bc, 1u);
                buf[s] = ((u64)k[j] << 11) | (u64)(unsigned)(g0 + j);
            }
        }
        __syncthreads();
        if (t < cless) {
            u64 my = buf[t];
            int r = 0;
            for (int j = 0; j < cless; j++) r += (buf[j] < my) ? 1 : 0;
            float v = __uint_as_float((unsigned)(my >> 11));
            outd[n * Kk + r] = acoshf(v) / sqc;
            outi[n * Kk + r] = (int)(my & 2047u);
        }
        // fill remaining slots from {v==lo}, smallest index first
        const int need = Kk - cless;
        unsigned eqm = 0u;
#pragma unroll
        for (int j = 0; j < 8; j++) if (k[j] == lo) eqm |= (1u << j);
        const float dv = acoshf(__uint_as_float(lo)) / sqc;
        for (int s = 0; s < need; s++) {
            int mi = 0x7FFFFFFF;
#pragma unroll
            for (int j = 0; j < 8; j++)
                if (eqm & (1u << j)) mi = min(mi, g0 + j);
#pragma unroll
            for (int off = 32; off; off >>= 1) mi = min(mi, __shfl_xor(mi, off, 64));
            __syncthreads();                 // protect prior wred/buf reads
            if ((t & 63) == 0) wred[w] = (unsigned)mi;
            __syncthreads();
            int m4 = (int)min(min(wred[0], wred[1]), min(wred[2], wred[3]));
            int j = m4 - g0;
            if (j >= 0 && j < 8 && (eqm & (1u << j))) {
                eqm &= ~(1u << j);
                outd[n * Kk + cless + s] = dv;
                outi[n * Kk + cless + s] = m4;
            }
        }
    }
}

// ---------------- sparse attention: one block per (b,n), all 8 heads --------
// R6 winner: stage K ONLY (coalescing transform for the gather); V's PV reads
// are naturally coalesced direct. LDS 34.4KB -> 4 blocks/CU.
// R9: Q + adist hoisted into regs BEFORE the staging barrier (loads overlap
// the K-gather; compiler cannot hoist loads across __syncthreads).
#define KSTR 520   // K row stride in f16 (512 + 8 pad -> bank-offset rows)
__global__ __launch_bounds__(256)
void attn_kernel(const f16* __restrict__ qkv, const float* __restrict__ adist,
                 const int* __restrict__ aidx, const float* __restrict__ scal,
                 int layer, f16* __restrict__ ao) {
    __shared__ __align__(16) f16 ks[Kk * KSTR];   // 33.3 KB: K rows only
    __shared__ float ps[Hh][Kk];
    __shared__ int   sidx[Kk];
    const int t = threadIdx.x;
    const int b = blockIdx.x >> 11, n = blockIdx.x & (Nn - 1);
    const float inv_tau = scal[2 + layer];
    const int h = t >> 5, j = t & 31;

    // hoisted loads: overlap the staging phase
    const f16* qrow = qkv + (size_t)(b * Nn + n) * 1536 + h * HDh;  // L1 bcast
    f16x8 qa[8];
#pragma unroll
    for (int i = 0; i < 8; i++) qa[i] = *(const f16x8*)(qrow + i * 8);
    const float sd = adist[n * Kk + j];

    if (t < Kk) sidx[t] = aidx[n * Kk + t];
    // stage K: 32 gathered rows x 1KB, fully coalesced (64 consecutive
    // 16B chunks per row, read by 64 consecutive threads)
#pragma unroll
    for (int q = 0; q < 8; q++) {
        int c = q * 256 + t;                 // 0..2047
        int jr = c >> 6, ci = c & 63;
        int row = aidx[n * Kk + jr];         // L1-cached re-read
        *(f16x8*)(ks + jr * KSTR + ci * 8) =
            *(const f16x8*)(qkv + (size_t)(b * Nn + row) * 1536 + 512 + ci * 8);
    }
    __syncthreads();

    float dot = 0.f;
#pragma unroll
    for (int i = 0; i < 8; i++) {
        f16x8 ka = *(const f16x8*)(ks + j * KSTR + h * HDh + i * 8);
#pragma unroll
        for (int m = 0; m < 4; m++) {
            f16x2 qp = {qa[i][2 * m], qa[i][2 * m + 1]};
            f16x2 kp = {ka[2 * m], ka[2 * m + 1]};
            dot = __builtin_amdgcn_fdot2(qp, kp, dot, false);
        }
    }
    float s = dot * SCALE_QK - sd * inv_tau;
    float mx = s;
#pragma unroll
    for (int off = 16; off; off >>= 1) mx = fmaxf(mx, __shfl_xor(mx, off, 64));
    float e = expf(s - mx);
    float sum = e;
#pragma unroll
    for (int off = 16; off; off >>= 1) sum += __shfl_xor(sum, off, 64);
    ps[h][j] = e / sum;
    __syncthreads();

    // PV: lane (h,d2); per jj a wave reads 256B contiguous (coalesced direct)
    const int d2 = t & 31;
    const size_t voff = 1024 + (size_t)h * HDh + d2 * 2;
    float a0 = 0.f, a1 = 0.f;
#pragma unroll
    for (int jj = 0; jj < Kk; jj++) {
        float p = ps[h][jj];
        f16x2 vv = *(const f16x2*)(qkv + (size_t)(b * Nn + sidx[jj]) * 1536 + voff);
        a0 = fmaf(p, (float)vv[0], a0);
        a1 = fmaf(p, (float)vv[1], a1);
    }
    f16x2 outv; outv[0] = (f16)a0; outv[1] = (f16)a1;
    *(f16x2*)(ao + (size_t)(b * Nn + n) * Dd + h * HDh + d2 * 2) = outv;
}

// ---------------- final projection: out = x[:, -1, :] @ Wout + bout ---------
__global__ __launch_bounds__(1024)
void out_kernel(const float* __restrict__ x, const float* __restrict__ Wout,
                const float* __restrict__ bout, float* __restrict__ out) {
    __shared__ float red[3][256];
    const int b = blockIdx.x;
    const int g = threadIdx.x >> 8, vc = threadIdx.x & 255;
    const float* xr = x + ((size_t)(b * Nn + (Nn - 1))) * Dd;
    float acc = 0.f;
    for (int d = g * 128; d < (g + 1) * 128; d++)
        acc = fmaf(xr[d], Wout[(size_t)d * Vv + vc], acc);
    if (g) red[g - 1][vc] = acc;
    __syncthreads();
    if (g == 0)
        out[b * Vv + vc] = acc + red[0][vc] + red[1][vc] + red[2][vc] + bout[vc];
}

// ---------------- workspace layout (bytes) — fully disjoint -----------------
static constexpr size_t X_OFF     = 0;          // 8388608  f32 x
static constexpr size_t XN16_OFF  = 8388608;    // 4194304  f16 xn
static constexpr size_t QKV16_OFF = 12582912;   // 12582912 f16 qkv
static constexpr size_t AO16_OFF  = 25165824;   // 4194304  f16 ao | f16 poshl (pre)
static constexpr size_t H1_OFF    = 29360128;   // 16777216 f16 h1 | f32 arg-matrix (pre)
static constexpr size_t AD_OFF    = 46137344;   // 262144
static constexpr size_t AI_OFF    = 46399488;   // 262144
static constexpr size_t SC_OFF    = 46661632;   // 256
static constexpr size_t HV_OFF    = 46661888;   // 2048
static constexpr size_t XX_OFF    = 46663936;   // 8192
static constexpr size_t BQKV_OFF  = 46672128;   // 32768
static constexpr size_t EMB16_OFF = 46704896;   // 262144
static constexpr size_t WBT_OFF   = 46967040;   // 524288
static constexpr size_t WQKVT_OFF = 47491328;   // 6291456  [L][1536][512]
static constexpr size_t WOT_OFF   = 53782784;   // 2097152  [L][512][512]
static constexpr size_t W1T_OFF   = 55879936;   // 8388608  [L][2048][512]
static constexpr size_t W2T_OFF   = 64268544;   // 8388608  [L][512][2048]
static constexpr size_t HP_OFF    = 72657152;   // 65536    hvec partials

extern "C" void kernel_launch(void* const* d_in, const int* in_sizes, int n_in,
                              void* d_out, int out_size, void* d_ws, size_t ws_size,
                              hipStream_t stream) {
    (void)in_sizes; (void)n_in; (void)out_size; (void)ws_size;
    const int*   hashes    = (const int*)  d_in[0];
    const int*   indices   = (const int*)  d_in[1];
    const float* emb       = (const float*)d_in[2];
    const float* hash_proj = (const float*)d_in[3];
    const float* Wb        = (const float*)d_in[4];
    const float* bb        = (const float*)d_in[5];
    const float* log_c     = (const float*)d_in[6];
    const float* pos_t     = (const float*)d_in[7];
    const float* Wq        = (const float*)d_in[8];
    const float* bq        = (const float*)d_in[9];
    const float* Wk        = (const float*)d_in[10];
    const float* bk        = (const float*)d_in[11];
    const float* Wv        = (const float*)d_in[12];
    const float* bv        = (const float*)d_in[13];
    const float* Wo        = (const float*)d_in[14];
    const float* bo        = (const float*)d_in[15];
    const float* W1        = (const float*)d_in[16];
    const float* b1        = (const float*)d_in[17];
    const float* W2        = (const float*)d_in[18];
    const float* b2        = (const float*)d_in[19];
    const float* g1        = (const float*)d_in[20];
    const float* be1       = (const float*)d_in[21];
    const float* g2        = (const float*)d_in[22];
    const float* be2       = (const float*)d_in[23];
    const float* log_tau   = (const float*)d_in[24];
    const float* Wout      = (const float*)d_in[25];
    const float* bout      = (const float*)d_in[26];

    char* ws = (char*)d_ws;
    float* x      = (float*)(ws + X_OFF);
    f16*   xn16   = (f16*)  (ws + XN16_OFF);
    f16*   qkv16  = (f16*)  (ws + QKV16_OFF);
    f16*   ao16   = (f16*)  (ws + AO16_OFF);
    f16*   h1     = (f16*)  (ws + H1_OFF);
    float* adist  = (float*)(ws + AD_OFF);
    int*   aidx   = (int*)  (ws + AI_OFF);
    float* scal   = (float*)(ws + SC_OFF);
    float* hvec   = (float*)(ws + HV_OFF);
    float* xxb    = (float*)(ws + XX_OFF);
    float* bqkv   = (float*)(ws + BQKV_OFF);
    f16*   emb16  = (f16*)  (ws + EMB16_OFF);
    f16*   Wbt    = (f16*)  (ws + WBT_OFF);
    f16*   Wqkvt  = (f16*)  (ws + WQKVT_OFF);
    f16*   Wot    = (f16*)  (ws + WOT_OFF);
    f16*   W1t    = (f16*)  (ws + W1T_OFF);
    f16*   W2t    = (f16*)  (ws + W2T_OFF);
    float* hpart  = (float*)(ws + HP_OFF);
    f16*   poshl  = (f16*)  (ws + AO16_OFF);   // alias, pre-loop only
    float* distb  = (float*)(ws + H1_OFF);     // alias, pre-loop only

    // --- weight prep (runs every call; graph-capture safe) ---
    prep_kernel<<<512, 256, 0, stream>>>(log_c, log_tau, scal, bq, bk, bv, bqkv, emb, emb16);
    hvec_part_kernel<<<32, 256, 0, stream>>>(hash_proj, Wb, hpart);
    hvec_red_kernel<<<2, 256, 0, stream>>>(hpart, hvec);
    trans_kernel<<<dim3(16, 16, 1), 256, 0, stream>>>(Wb, Wbt, 512, 512, 0, 0);
    trans4_kernel<<<dim3(16, 16, 16), 256, 0, stream>>>(Wq, Wk, Wv, Wo, Wqkvt, Wot);
    trans_kernel<<<dim3(64, 16, Ll), 256, 0, stream>>>(W1, W1t, 512, 2048, 1048576, 1048576);
    trans_kernel<<<dim3(16, 64, Ll), 256, 0, stream>>>(W2, W2t, 2048, 512, 1048576, 1048576);

    // --- input projection: x = emb16[indices] @ Wbt^T + hash*hvec + bb (f32 out)
    mgemm<32, 64, true, true, false, false, false><<<dim3(8, 128), 256, 0, stream>>>(
        emb16, Wbt, bb, indices, hashes, hvec, nullptr, x, Mrows, Dd, Dd);

    // --- kNN preprocessing: expmap (hi/lo split) -> MFMA arg -> topk+acosh ---
    expmap_kernel<<<Nn, 256, 0, stream>>>(pos_t, scal, poshl, xxb);
    mdist_kernel<<<528, 256, 0, stream>>>(poshl, xxb, scal, distb);
    topk_kernel<<<Nn, 256, 0, stream>>>(distb, scal, adist, aidx);

    for (int l = 0; l < Ll; l++) {
        ln_kernel<<<Mrows / 4, 256, 0, stream>>>(x, g1 + l * Dd, be1 + l * Dd, xn16);
        // fused QKV: M x 1536, f16 out
        mgemm<64, 128, false, false, false, false, true><<<dim3(12, 64), 256, 0, stream>>>(
            xn16, Wqkvt + (size_t)l * 786432, bqkv + l * 1536,
            nullptr, nullptr, nullptr, nullptr, qkv16, Mrows, 1536, Dd);
        attn_kernel<<<Bb * Nn, 256, 0, stream>>>(qkv16, adist, aidx, scal, l, ao16);
        // Wo + residual, f32 out — TM=32, grid 1024 -> 4 blocks/CU
        mgemm<32, 64, false, false, false, true, false><<<dim3(8, 128), 256, 0, stream>>>(
            ao16, Wot + (size_t)l * 262144, bo + l * Dd,
            nullptr, nullptr, nullptr, x, x, Mrows, Dd, Dd);
        ln_kernel<<<Mrows / 4, 256, 0, stream>>>(x, g2 + l * Dd, be2 + l * Dd, xn16);
        // W1 + GELU, f16 out — TM=128xTN=128: staged 192->128 MB, 2 blocks/CU exact
        mgemm<128, 128, false, false, true, false, true><<<dim3(16, 32), 256, 0, stream>>>(
            xn16, W1t + (size_t)l * 1048576, b1 + l * 4 * Dd,
            nullptr, nullptr, nullptr, nullptr, h1, Mrows, 4 * Dd, Dd);
        // W2 + residual, f32 out — TM=128xTN=64: staged 384->192 MB, 1 block/CU exact
        mgemm<128, 64, false, false, false, true, false><<<dim3(8, 32), 256, 0, stream>>>(
            h1, W2t + (size_t)l * 1048576, b2 + l * Dd,
            nullptr, nullptr, nullptr, x, x, Mrows, Dd, 4 * Dd);
    }

    out_kernel<<<Bb, 1024, 0, stream>>>(x, Wout, bout, (float*)d_out);
}

// Round 10
// 567.252 us; speedup vs baseline: 1.0420x; 1.0420x over previous
//
#include <hip/hip_runtime.h>
#include <hip/hip_bf16.h>
#include <math.h>

// Problem constants
#define Bb 2
#define Nn 2048
#define Dd 512
#define Hh 8
#define Ll 4
#define Kk 32
#define Vv 256
#define HDh 64
#define Mrows (Bb*Nn)   // 4096

static constexpr float SCALE_QK = 0.125f;           // 1/sqrt(64)
static constexpr float INV_MOD = 1.0f / 4294967296.0f;

typedef _Float16 f16;
typedef _Float16 f16x8 __attribute__((ext_vector_type(8)));
typedef _Float16 f16x4 __attribute__((ext_vector_type(4)));
typedef _Float16 f16x2 __attribute__((ext_vector_type(2)));
typedef float f32x4 __attribute__((ext_vector_type(4)));
typedef unsigned long long u64;

// ---- async global->LDS, 16B per lane (dest must be linear: base+lane*16) ---
#define AS_GLOBAL(p) ((const __attribute__((address_space(1))) void*)(p))
#define AS_LDS(p)    ((__attribute__((address_space(3))) void*)(p))
__device__ __forceinline__ void gload16(const f16* g, f16* l) {
    __builtin_amdgcn_global_load_lds(AS_GLOBAL(g), AS_LDS(l), 16, 0, 0);
}

// ------- fused tiny prep: scal + bias concat + emb f32->f16 -----------------
__global__ __launch_bounds__(256)
void prep_kernel(const float* __restrict__ log_c, const float* __restrict__ log_tau,
                 float* __restrict__ scal,
                 const float* __restrict__ bq, const float* __restrict__ bk,
                 const float* __restrict__ bv, float* __restrict__ bqkv,
                 const float* __restrict__ emb, f16* __restrict__ emb16) {
    int id = blockIdx.x * 256 + threadIdx.x;     // 512 blocks x 256 = 131072
    if (id < Vv * Dd) emb16[id] = (f16)emb[id];
    if (id < Ll * 1536) {
        int l = id / 1536, r = id % 1536;
        const float* src = (r < 512) ? bq : ((r < 1024) ? bk : bv);
        bqkv[id] = src[l * 512 + (r & 511)];
    }
    if (id == 0) {
        float c = expf(log_c[0]);
        scal[0] = c;
        scal[1] = sqrtf(c);
    }
    if (id < Ll) scal[2 + id] = 1.0f / (expf(log_tau[id]) + 1e-8f);
}

// ------- hvec split-K GEMV, coalesced: part[b][n] = sum_{kx in slice} -------
__global__ __launch_bounds__(256)
void hvec_part_kernel(const float* __restrict__ hash_proj,
                      const float* __restrict__ Wb,
                      float* __restrict__ part) {
    const int b = blockIdx.x;            // 32 blocks, 16 k-rows each
    const int t = threadIdx.x;
    float a0 = 0.f, a1 = 0.f;
#pragma unroll
    for (int i = 0; i < 16; i++) {
        int kx = b * 16 + i;
        float hp = hash_proj[kx];
        const float* wr = Wb + (size_t)(Dd + kx) * Dd;
        a0 = fmaf(hp, wr[t], a0);
        a1 = fmaf(hp, wr[t + 256], a1);
    }
    part[b * Dd + t]       = a0;
    part[b * Dd + t + 256] = a1;
}
__global__ __launch_bounds__(256)
void hvec_red_kernel(const float* __restrict__ part, float* __restrict__ hvec) {
    const int n = blockIdx.x * 256 + threadIdx.x;   // 2 blocks
    float acc = 0.f;
#pragma unroll
    for (int b = 0; b < 32; b++) acc += part[b * Dd + n];
    hvec[n] = acc;
}

// ---------------- convert + transpose: W (K x N f32) -> Wt (N x K f16) ------
__global__ __launch_bounds__(256)
void trans_kernel(const float* __restrict__ src, f16* __restrict__ dst,
                  int K, int N, long sStride, long dStride) {
    __shared__ float tile[32][33];
    const float* s = src + blockIdx.z * sStride;
    f16* d = dst + blockIdx.z * dStride;
    int k0 = blockIdx.y * 32, n0 = blockIdx.x * 32;
    int tx = threadIdx.x & 31, ty = threadIdx.x >> 5;   // ty 0..7
#pragma unroll
    for (int i = 0; i < 32; i += 8)
        tile[ty + i][tx] = s[(long)(k0 + ty + i) * N + n0 + tx];
    __syncthreads();
#pragma unroll
    for (int i = 0; i < 32; i += 8)
        d[(long)(n0 + ty + i) * K + k0 + tx] = (f16)tile[tx][ty + i];
}

// ---- merged transpose for the four 512x512 weight families (z = w*4 + l) ---
__global__ __launch_bounds__(256)
void trans4_kernel(const float* __restrict__ Wq, const float* __restrict__ Wk,
                   const float* __restrict__ Wv, const float* __restrict__ Wo,
                   f16* __restrict__ Wqkvt, f16* __restrict__ Wot) {
    __shared__ float tile[32][33];
    const int which = blockIdx.z >> 2, l = blockIdx.z & 3;
    const float* s;
    f16* d;
    switch (which) {
        case 0: s = Wq + (size_t)l * 262144; d = Wqkvt + (size_t)l * 786432;          break;
        case 1: s = Wk + (size_t)l * 262144; d = Wqkvt + (size_t)l * 786432 + 262144; break;
        case 2: s = Wv + (size_t)l * 262144; d = Wqkvt + (size_t)l * 786432 + 524288; break;
        default:s = Wo + (size_t)l * 262144; d = Wot   + (size_t)l * 262144;          break;
    }
    int k0 = blockIdx.y * 32, n0 = blockIdx.x * 32;
    int tx = threadIdx.x & 31, ty = threadIdx.x >> 5;
#pragma unroll
    for (int i = 0; i < 32; i += 8)
        tile[ty + i][tx] = s[(long)(k0 + ty + i) * 512 + n0 + tx];
    __syncthreads();
#pragma unroll
    for (int i = 0; i < 32; i += 8)
        d[(long)(n0 + ty + i) * 512 + k0 + tx] = (f16)tile[tx][ty + i];
}

// ---------------- MFMA f16 GEMM: C = op(A @ Wt^T + bias), BK=64 -------------
// R10: W1/W2 tiles REVERTED to the R8 winners (R9 post-mortem: 128-tall
// tiles cut staged traffic but dropped occupancy to 1-2 blocks/CU = 4-8
// waves/CU; latency exposure beat the traffic saving). W1=64x128 (3 blk/CU),
// W2=Wo=input=32x64 (4 blk/CU). TN=64: 3 LDS buffers, depth-2 prefetch,
// counted vmcnt(NCHT). TN=128: 2-buffer, exact vmcnt(0). LDS dest linear;
// XOR bank-swizzle folded into pre-swizzled GLOBAL source.
template<int TM, int TN, bool GATHER, bool RANK1, bool GELU, bool RES, bool OUT16>
__global__ __launch_bounds__(256)
void mgemm(const f16* __restrict__ A, const f16* __restrict__ Wt,
           const float* __restrict__ bias,
           const int* __restrict__ gidx,
           const int* __restrict__ hashes, const float* __restrict__ hvec,
           const float* __restrict__ resid,
           void* __restrict__ Cout, int M, int N, int K) {
    constexpr int WRN = (TN == 64) ? 2 : ((TM == 128) ? 2 : 1);
    constexpr int WCN = 4 / WRN;              // wave-grid cols
    constexpr int WRE = TM / WRN;             // wave row extent (16/32/64)
    constexpr int NIT = WRE / 16;             // row tiles/wave (1/2/4)
    constexpr int COLE = TN / WCN;            // wave col extent (32 or 64)
    constexpr int NJT = COLE / 16;            // col tiles/wave (2 or 4)
    constexpr int ACH = TM * 8;               // A chunks (16B), BK=64 f16 = 8/row
    constexpr int BCH = TN * 8;
    constexpr int NCH = ACH + BCH;
    constexpr int NCHT = NCH / 256;           // 3,4,6,8
    constexpr int NBUF = (TN == 64) ? 3 : 2;
    static_assert(NCH % 256 == 0, "chunk count must tile the block");
    __shared__ __align__(16) f16 sm[NBUF][NCH * 8];
    const int t = threadIdx.x;
    const int lane = t & 63;
    const int w = t >> 6;
    const int wr = w / WCN, wc = w % WCN;
    const int i0 = blockIdx.y * TM, j0 = blockIdx.x * TN;

    const f16* gsrc[NCHT];
#pragma unroll
    for (int q = 0; q < NCHT; q++) {
        int c = t + q * 256;
        if (c < ACH) {
            int m = c >> 3, kb = (c & 7) ^ (m & 7);
            long row = GATHER ? (long)gidx[i0 + m] : (long)(i0 + m);
            gsrc[q] = A + row * K + kb * 8;
        } else {
            int cc = c - ACH;
            int n = cc >> 3, kb = (cc & 7) ^ (n & 7);
            gsrc[q] = Wt + (long)(j0 + n) * K + kb * 8;
        }
    }

    f32x4 acc[NIT][NJT];
#pragma unroll
    for (int i = 0; i < NIT; i++)
#pragma unroll
        for (int j = 0; j < NJT; j++) acc[i][j] = (f32x4){0.f, 0.f, 0.f, 0.f};

    auto compute = [&](const f16* rbuf) {
#pragma unroll
        for (int kh = 0; kh < 2; kh++) {
            f16x8 af[NIT], bf[NJT];
#pragma unroll
            for (int i = 0; i < NIT; i++) {
                int m = wr * WRE + i * 16 + (lane & 15);
                int sl = m * 8 + ((kh * 4 + (lane >> 4)) ^ (m & 7));
                af[i] = *(const f16x8*)(rbuf + sl * 8);
            }
#pragma unroll
            for (int j = 0; j < NJT; j++) {
                int n = wc * COLE + j * 16 + (lane & 15);
                int sl = ACH + n * 8 + ((kh * 4 + (lane >> 4)) ^ (n & 7));
                bf[j] = *(const f16x8*)(rbuf + sl * 8);
            }
#pragma unroll
            for (int i = 0; i < NIT; i++)
#pragma unroll
                for (int j = 0; j < NJT; j++)
                    acc[i][j] = __builtin_amdgcn_mfma_f32_16x16x32_f16(af[i], bf[j], acc[i][j], 0, 0, 0);
        }
    };

    if constexpr (TN == 64) {
        static_assert(NCHT == 3 || NCHT == 4 || NCHT == 6, "vmcnt immediate coverage");
        const int T = K >> 6;
        // prologue: sets 0 and 1
#pragma unroll
        for (int q = 0; q < NCHT; q++) gload16(gsrc[q],      &sm[0][(t + q * 256) * 8]);
#pragma unroll
        for (int q = 0; q < NCHT; q++) gload16(gsrc[q] + 64, &sm[1][(t + q * 256) * 8]);
        f16 *bA = sm[0], *bB = sm[1], *bC = sm[2];
        for (int tt = 0; tt < T - 1; ++tt) {
            // set tt landed; set tt+1 (NCHT loads) stays in flight
            if constexpr (NCHT == 3)      asm volatile("s_waitcnt vmcnt(3)" ::: "memory");
            else if constexpr (NCHT == 4) asm volatile("s_waitcnt vmcnt(4)" ::: "memory");
            else                          asm volatile("s_waitcnt vmcnt(6)" ::: "memory");
            __syncthreads();
            if (tt + 2 < T) {
                const int kt2 = (tt + 2) << 6;
#pragma unroll
                for (int q = 0; q < NCHT; q++)
                    gload16(gsrc[q] + kt2, bC + (t + q * 256) * 8);
            }
            compute(bA);
            f16* tmp = bA; bA = bB; bB = bC; bC = tmp;
        }
        asm volatile("s_waitcnt vmcnt(0)" ::: "memory");
        __syncthreads();
        compute(bA);
    } else {
        // 2-buffer, exact vmcnt(0) (single set in flight at the wait)
#pragma unroll
        for (int q = 0; q < NCHT; q++)
            gload16(gsrc[q], &sm[0][(t + q * 256) * 8]);
        auto step = [&](int kt, const f16* rbuf, f16* wbuf) {
            asm volatile("s_waitcnt vmcnt(0)" ::: "memory");
            __syncthreads();                  // rbuf staged + wbuf reads done
            if (kt + 64 < K) {
#pragma unroll
                for (int q = 0; q < NCHT; q++)
                    gload16(gsrc[q] + kt + 64, wbuf + (t + q * 256) * 8);
            }
            compute(rbuf);
        };
        for (int kt = 0; kt < K; kt += 128) { // K/64 even at all call sites
            step(kt,      sm[0], sm[1]);
            step(kt + 64, sm[1], sm[0]);
        }
    }

    // epilogue: C/D layout col=lane&15, row=(lane>>4)*4+v
    float* Cf = (float*)Cout;
    f16*   Ch = (f16*)Cout;
#pragma unroll
    for (int i = 0; i < NIT; i++) {
        int rbase = i0 + wr * WRE + i * 16 + ((lane >> 4) << 2);
#pragma unroll
        for (int v = 0; v < 4; v++) {
            int row = rbase + v;
            float hterm = RANK1 ? (float)hashes[row] * INV_MOD : 0.f;
#pragma unroll
            for (int j = 0; j < NJT; j++) {
                int col = j0 + wc * COLE + j * 16 + (lane & 15);
                float val = acc[i][j][v] + bias[col];
                if (RANK1) val += hterm * hvec[col];
                if (GELU)  val = 0.5f * val * (1.f + erff(val * 0.7071067811865475f));
                if (RES)   val += resid[(long)row * N + col];
                if (OUT16) Ch[(long)row * N + col] = (f16)val;
                else       Cf[(long)row * N + col] = val;
            }
        }
    }
}

// ---------------- MFMA Poincare "arg" matrix (BK=64, TM=TN=64) --------------
// poshl: 2048 x 1024 f16, row = [hi(512) | lo(512)], pos ~= hi+lo (22-bit).
// Writes arg = max(1 + 2c*d2/denom, 1) — MONOTONE in dist, top-k on arg ==
// top-k on dist; acosh deferred to winners (topk_kernel).
// R9 keeper: arg(i,j) is BIT-IDENTICAL to arg(j,i) (products commute, same
// MFMA reduce order) -> only 528 upper-triangle tiles computed; mirror tile
// written via LDS-transposed coalesced pass. -48% MFMA/fetch, zero numerics.
__global__ __launch_bounds__(256)
void mdist_kernel(const f16* __restrict__ poshl, const float* __restrict__ xx,
                  const float* __restrict__ scal, float* __restrict__ dist) {
    constexpr int TM = 64, TN = 64;
    constexpr int ACH = TM * 8, BCH = TN * 8, NCH = ACH + BCH;   // 1024
    constexpr int NCHT = NCH / 256;                               // 4
    constexpr int KK = 1024;
    __shared__ __align__(16) f16 sm[3][NCH * 8];
    const int t = threadIdx.x;
    const int lane = t & 63;
    const int w = t >> 6;
    const int wr = w >> 1, wc = w & 1;

    // triangular decode: bi -> (by, bx), by <= bx; S(r) = 32r - r(r-1)/2
    const int bi = blockIdx.x;
    int r = (int)((65.0f - sqrtf(4225.0f - 8.0f * (float)bi)) * 0.5f);
    while (32 * (r + 1) - ((r + 1) * r) / 2 <= bi) r++;
    while (32 * r - (r * (r - 1)) / 2 > bi) r--;
    const int by = r, bx = r + (bi - (32 * r - (r * (r - 1)) / 2));
    const int i0 = by * TM, j0 = bx * TN;

    const f16* gsrc[NCHT];
#pragma unroll
    for (int q = 0; q < NCHT; q++) {
        int c = t + q * 256;
        if (c < ACH) {
            int m = c >> 3, kb = (c & 7) ^ (m & 7);
            gsrc[q] = poshl + (long)(i0 + m) * KK + kb * 8;
        } else {
            int cc = c - ACH;
            int n = cc >> 3, kb = (cc & 7) ^ (n & 7);
            gsrc[q] = poshl + (long)(j0 + n) * KK + kb * 8;
        }
    }

    f32x4 acc[2][2];
#pragma unroll
    for (int i = 0; i < 2; i++)
#pragma unroll
        for (int j = 0; j < 2; j++) acc[i][j] = (f32x4){0.f, 0.f, 0.f, 0.f};

    auto compute = [&](const f16* rbuf) {
#pragma unroll
        for (int kh = 0; kh < 2; kh++) {
            f16x8 af[2], bf[2];
#pragma unroll
            for (int i = 0; i < 2; i++) {
                int m = wr * 32 + i * 16 + (lane & 15);
                int sl = m * 8 + ((kh * 4 + (lane >> 4)) ^ (m & 7));
                af[i] = *(const f16x8*)(rbuf + sl * 8);
            }
#pragma unroll
            for (int j = 0; j < 2; j++) {
                int n = wc * 32 + j * 16 + (lane & 15);
                int sl = ACH + n * 8 + ((kh * 4 + (lane >> 4)) ^ (n & 7));
                bf[j] = *(const f16x8*)(rbuf + sl * 8);
            }
#pragma unroll
            for (int i = 0; i < 2; i++)
#pragma unroll
                for (int j = 0; j < 2; j++)
                    acc[i][j] = __builtin_amdgcn_mfma_f32_16x16x32_f16(af[i], bf[j], acc[i][j], 0, 0, 0);
        }
    };

#pragma unroll
    for (int q = 0; q < NCHT; q++) gload16(gsrc[q],      &sm[0][(t + q * 256) * 8]);
#pragma unroll
    for (int q = 0; q < NCHT; q++) gload16(gsrc[q] + 64, &sm[1][(t + q * 256) * 8]);
    f16 *bA = sm[0], *bB = sm[1], *bC = sm[2];
    constexpr int T = KK >> 6;                // 16
    for (int tt = 0; tt < T - 1; ++tt) {
        asm volatile("s_waitcnt vmcnt(4)" ::: "memory");
        __syncthreads();
        if (tt + 2 < T) {
            const int kt2 = (tt + 2) << 6;
#pragma unroll
            for (int q = 0; q < NCHT; q++)
                gload16(gsrc[q] + kt2, bC + (t + q * 256) * 8);
        }
        compute(bA);
        f16* tmp = bA; bA = bB; bB = bC; bC = tmp;
    }
    asm volatile("s_waitcnt vmcnt(0)" ::: "memory");
    __syncthreads();
    compute(bA);

    // epilogue: compute args into regs, write direct tile; mirror via LDS
    const float c = scal[0];
    float vals[2][4][2];
#pragma unroll
    for (int i = 0; i < 2; i++) {
        int rbase = i0 + wr * 32 + i * 16 + ((lane >> 4) << 2);
#pragma unroll
        for (int v = 0; v < 4; v++) {
            int row = rbase + v;
            float xi = xx[row];
#pragma unroll
            for (int j = 0; j < 2; j++) {
                int col = j0 + wc * 32 + j * 16 + (lane & 15);
                float xj = xx[col];
                float d2 = fmaxf(xi + xj - 2.f * acc[i][j][v], 0.f);
                float denom = (1.f - c * xi) * (1.f - c * xj) + 1e-8f;
                float arg = fmaxf(1.f + 2.f * c * d2 / denom, 1.f);
                vals[i][v][j] = arg;
                dist[(long)row * Nn + col] = arg;
            }
        }
    }
    if (bx != by) {
        __syncthreads();                      // all compute reads of sm done
        float* trf = (float*)sm;              // [64][65] padded transpose tile
#pragma unroll
        for (int i = 0; i < 2; i++) {
#pragma unroll
            for (int v = 0; v < 4; v++) {
                int rw = wr * 32 + i * 16 + ((lane >> 4) << 2) + v;
#pragma unroll
                for (int j = 0; j < 2; j++) {
                    int cl = wc * 32 + j * 16 + (lane & 15);
                    trf[cl * 65 + rw] = vals[i][v][j];
                }
            }
        }
        __syncthreads();
        const int cl = t >> 2, q4 = t & 3;
#pragma unroll
        for (int s = 0; s < 4; s++) {
            int rw = q4 * 16 + s * 4;
            float4 wv;
            wv.x = trf[cl * 65 + rw];
            wv.y = trf[cl * 65 + rw + 1];
            wv.z = trf[cl * 65 + rw + 2];
            wv.w = trf[cl * 65 + rw + 3];
            *(float4*)(dist + (long)(j0 + cl) * Nn + i0 + rw) = wv;
        }
    }
}

// ---------------- LayerNorm (512): 4 rows/block, 1 wave/row, float4 ---------
__global__ __launch_bounds__(256)
void ln_kernel(const float* __restrict__ x, const float* __restrict__ g,
               const float* __restrict__ be, f16* __restrict__ xn) {
    const int row = blockIdx.x * 4 + (threadIdx.x >> 6);
    const int t = threadIdx.x & 63;
    const float4* xr = (const float4*)(x + (size_t)row * Dd);
    float4 v0 = xr[t], v1 = xr[t + 64];
    float s = v0.x + v0.y + v0.z + v0.w + v1.x + v1.y + v1.z + v1.w;
#pragma unroll
    for (int off = 32; off; off >>= 1) s += __shfl_xor(s, off, 64);
    float mean = s * (1.f / Dd);
    float d0x = v0.x - mean, d0y = v0.y - mean, d0z = v0.z - mean, d0w = v0.w - mean;
    float d1x = v1.x - mean, d1y = v1.y - mean, d1z = v1.z - mean, d1w = v1.w - mean;
    float q = d0x*d0x + d0y*d0y + d0z*d0z + d0w*d0w
            + d1x*d1x + d1y*d1y + d1z*d1z + d1w*d1w;
#pragma unroll
    for (int off = 32; off; off >>= 1) q += __shfl_xor(q, off, 64);
    float rstd = rsqrtf(q * (1.f / Dd) + 1e-5f);
    float4 g0 = ((const float4*)g)[t], g1v = ((const float4*)g)[t + 64];
    float4 b0 = ((const float4*)be)[t], b1v = ((const float4*)be)[t + 64];
    f16* xo = xn + (size_t)row * Dd;
    f16x4 o0, o1;
    o0[0] = (f16)(d0x * rstd * g0.x + b0.x);
    o0[1] = (f16)(d0y * rstd * g0.y + b0.y);
    o0[2] = (f16)(d0z * rstd * g0.z + b0.z);
    o0[3] = (f16)(d0w * rstd * g0.w + b0.w);
    o1[0] = (f16)(d1x * rstd * g1v.x + b1v.x);
    o1[1] = (f16)(d1y * rstd * g1v.y + b1v.y);
    o1[2] = (f16)(d1z * rstd * g1v.z + b1v.z);
    o1[3] = (f16)(d1w * rstd * g1v.w + b1v.w);
    *(f16x4*)(xo + t * 4)         = o0;
    *(f16x4*)(xo + (t + 64) * 4)  = o1;
}

// ---------------- expmap0 -> poshl (f16 hi|lo), xx = |pos|^2 (f32) ----------
__global__ __launch_bounds__(256)
void expmap_kernel(const float* __restrict__ vt, const float* __restrict__ scal,
                   f16* __restrict__ poshl, float* __restrict__ xx) {
    __shared__ float red[256];
    const int row = blockIdx.x, t = threadIdx.x;
    const float* vr = vt + (size_t)row * Dd;
    float v0 = vr[t], v1 = vr[t + 256];
    red[t] = v0 * v0 + v1 * v1;
    __syncthreads();
    for (int off = 128; off; off >>= 1) {
        if (t < off) red[t] += red[t + off];
        __syncthreads();
    }
    float total = red[0];
    float vn = fmaxf(sqrtf(total), 1e-8f);
    float sc = scal[1];
    float factor = tanhf(sc * vn) / (sc * vn);
    float p0 = factor * v0, p1 = factor * v1;
    f16 h0 = (f16)p0, h1 = (f16)p1;
    f16* pr = poshl + (size_t)row * 1024;
    pr[t]             = h0;
    pr[t + 256]       = h1;
    pr[512 + t]       = (f16)(p0 - (float)h0);
    pr[512 + t + 256] = (f16)(p1 - (float)h1);
    if (t == 0) xx[row] = factor * factor * total;
}

// ---------------- top-K=32: bisection threshold + rank-select ---------------
__global__ __launch_bounds__(256)
void topk_kernel(const float* __restrict__ dist, const float* __restrict__ scal,
                 float* __restrict__ outd, int* __restrict__ outi) {
    __shared__ unsigned wred[4];
    __shared__ unsigned bc;
    __shared__ __align__(8) u64 buf[128];
    const int t = threadIdx.x;
    const int w = t >> 6;
    const int n = blockIdx.x;
    const float sqc = scal[1];
    const uint4* dr = (const uint4*)(dist + (size_t)n * Nn);

    uint4 va = dr[t * 2];
    uint4 vb = dr[t * 2 + 1];
    unsigned k[8] = {va.x, va.y, va.z, va.w, vb.x, vb.y, vb.z, vb.w};
    const int g0 = t * 8;

    // ---- bisection: find hi with 32 <= cnt(v < hi) <= 96 (or hi-lo==1) ----
    unsigned lo = 0x3F800000u;   // 1.0f bits: cnt(v<1.0)==0 (args >= 1)
    unsigned hi = 0x7F800001u;   // above +inf bits: counts all 2048
    unsigned chi = 2048u;
    while (chi > 96u && (hi - lo) > 1u) {
        unsigned mid = lo + ((hi - lo) >> 1);
        int c = 0;
#pragma unroll
        for (int j = 0; j < 8; j++) c += (k[j] < mid) ? 1 : 0;
#pragma unroll
        for (int off = 32; off; off >>= 1) c += __shfl_xor(c, off, 64);
        __syncthreads();                     // protect wred reads of prev iter
        if ((t & 63) == 0) wred[w] = (unsigned)c;
        __syncthreads();
        unsigned ct = wred[0] + wred[1] + wred[2] + wred[3];
        if (ct >= 32u) { hi = mid; chi = ct; } else { lo = mid; }
    }

    if (chi <= 96u) {
        // ---- normal path: compact candidates, rank-select ----
        if (t == 0) bc = 0u;
        __syncthreads();
#pragma unroll
        for (int j = 0; j < 8; j++) {
            if (k[j] < hi) {
                unsigned s = atomicAdd(&bc, 1u);
                buf[s] = ((u64)k[j] << 11) | (u64)(unsigned)(g0 + j);
            }
        }
        __syncthreads();
        const int m = (int)chi;
        if (t < m) {
            u64 my = buf[t];
            int r = 0;
            for (int j = 0; j < m; j++) r += (buf[j] < my) ? 1 : 0;
            if (r < Kk) {
                float v = __uint_as_float((unsigned)(my >> 11));
                outd[n * Kk + r] = acoshf(v) / sqc;
                outi[n * Kk + r] = (int)(my & 2047u);
            }
        }
    } else {
        // ---- exhaustion path: hi == lo+1; {v<hi} = {v<lo} U {v==lo} ----
        int c = 0;
#pragma unroll
        for (int j = 0; j < 8; j++) c += (k[j] < lo) ? 1 : 0;
#pragma unroll
        for (int off = 32; off; off >>= 1) c += __shfl_xor(c, off, 64);
        __syncthreads();
        if ((t & 63) == 0) wred[w] = (unsigned)c;
        if (t == 0) bc = 0u;
        __syncthreads();
        const int cless = (int)(wred[0] + wred[1] + wred[2] + wred[3]);
#pragma unroll
        for (int j = 0; j < 8; j++) {
            if (k[j] < lo) {
                unsigned s = atomicAdd(&bc, 1u);
                buf[s] = ((u64)k[j] << 11) | (u64)(unsigned)(g0 + j);
            }
        }
        __syncthreads();
        if (t < cless) {
            u64 my = buf[t];
            int r = 0;
            for (int j = 0; j < cless; j++) r += (buf[j] < my) ? 1 : 0;
            float v = __uint_as_float((unsigned)(my >> 11));
            outd[n * Kk + r] = acoshf(v) / sqc;
            outi[n * Kk + r] = (int)(my & 2047u);
        }
        // fill remaining slots from {v==lo}, smallest index first
        const int need = Kk - cless;
        unsigned eqm = 0u;
#pragma unroll
        for (int j = 0; j < 8; j++) if (k[j] == lo) eqm |= (1u << j);
        const float dv = acoshf(__uint_as_float(lo)) / sqc;
        for (int s = 0; s < need; s++) {
            int mi = 0x7FFFFFFF;
#pragma unroll
            for (int j = 0; j < 8; j++)
                if (eqm & (1u << j)) mi = min(mi, g0 + j);
#pragma unroll
            for (int off = 32; off; off >>= 1) mi = min(mi, __shfl_xor(mi, off, 64));
            __syncthreads();                 // protect prior wred/buf reads
            if ((t & 63) == 0) wred[w] = (unsigned)mi;
            __syncthreads();
            int m4 = (int)min(min(wred[0], wred[1]), min(wred[2], wred[3]));
            int j = m4 - g0;
            if (j >= 0 && j < 8 && (eqm & (1u << j))) {
                eqm &= ~(1u << j);
                outd[n * Kk + cless + s] = dv;
                outi[n * Kk + cless + s] = m4;
            }
        }
    }
}

// ---------------- sparse attention: one block per (b,n), all 8 heads --------
// R6 winner: stage K ONLY (coalescing transform for the gather); V's PV reads
// are naturally coalesced direct. LDS 34.4KB -> 4 blocks/CU.
// R9 keeper: Q + adist hoisted into regs BEFORE the staging barrier (loads
// overlap the K-gather; compiler cannot hoist loads across __syncthreads).
#define KSTR 520   // K row stride in f16 (512 + 8 pad -> bank-offset rows)
__global__ __launch_bounds__(256)
void attn_kernel(const f16* __restrict__ qkv, const float* __restrict__ adist,
                 const int* __restrict__ aidx, const float* __restrict__ scal,
                 int layer, f16* __restrict__ ao) {
    __shared__ __align__(16) f16 ks[Kk * KSTR];   // 33.3 KB: K rows only
    __shared__ float ps[Hh][Kk];
    __shared__ int   sidx[Kk];
    const int t = threadIdx.x;
    const int b = blockIdx.x >> 11, n = blockIdx.x & (Nn - 1);
    const float inv_tau = scal[2 + layer];
    const int h = t >> 5, j = t & 31;

    // hoisted loads: overlap the staging phase
    const f16* qrow = qkv + (size_t)(b * Nn + n) * 1536 + h * HDh;  // L1 bcast
    f16x8 qa[8];
#pragma unroll
    for (int i = 0; i < 8; i++) qa[i] = *(const f16x8*)(qrow + i * 8);
    const float sd = adist[n * Kk + j];

    if (t < Kk) sidx[t] = aidx[n * Kk + t];
    // stage K: 32 gathered rows x 1KB, fully coalesced (64 consecutive
    // 16B chunks per row, read by 64 consecutive threads)
#pragma unroll
    for (int q = 0; q < 8; q++) {
        int c = q * 256 + t;                 // 0..2047
        int jr = c >> 6, ci = c & 63;
        int row = aidx[n * Kk + jr];         // L1-cached re-read
        *(f16x8*)(ks + jr * KSTR + ci * 8) =
            *(const f16x8*)(qkv + (size_t)(b * Nn + row) * 1536 + 512 + ci * 8);
    }
    __syncthreads();

    float dot = 0.f;
#pragma unroll
    for (int i = 0; i < 8; i++) {
        f16x8 ka = *(const f16x8*)(ks + j * KSTR + h * HDh + i * 8);
#pragma unroll
        for (int m = 0; m < 4; m++) {
            f16x2 qp = {qa[i][2 * m], qa[i][2 * m + 1]};
            f16x2 kp = {ka[2 * m], ka[2 * m + 1]};
            dot = __builtin_amdgcn_fdot2(qp, kp, dot, false);
        }
    }
    float s = dot * SCALE_QK - sd * inv_tau;
    float mx = s;
#pragma unroll
    for (int off = 16; off; off >>= 1) mx = fmaxf(mx, __shfl_xor(mx, off, 64));
    float e = expf(s - mx);
    float sum = e;
#pragma unroll
    for (int off = 16; off; off >>= 1) sum += __shfl_xor(sum, off, 64);
    ps[h][j] = e / sum;
    __syncthreads();

    // PV: lane (h,d2); per jj a wave reads 256B contiguous (coalesced direct)
    const int d2 = t & 31;
    const size_t voff = 1024 + (size_t)h * HDh + d2 * 2;
    float a0 = 0.f, a1 = 0.f;
#pragma unroll
    for (int jj = 0; jj < Kk; jj++) {
        float p = ps[h][jj];
        f16x2 vv = *(const f16x2*)(qkv + (size_t)(b * Nn + sidx[jj]) * 1536 + voff);
        a0 = fmaf(p, (float)vv[0], a0);
        a1 = fmaf(p, (float)vv[1], a1);
    }
    f16x2 outv; outv[0] = (f16)a0; outv[1] = (f16)a1;
    *(f16x2*)(ao + (size_t)(b * Nn + n) * Dd + h * HDh + d2 * 2) = outv;
}

// ---------------- final projection: out = x[:, -1, :] @ Wout + bout ---------
__global__ __launch_bounds__(1024)
void out_kernel(const float* __restrict__ x, const float* __restrict__ Wout,
                const float* __restrict__ bout, float* __restrict__ out) {
    __shared__ float red[3][256];
    const int b = blockIdx.x;
    const int g = threadIdx.x >> 8, vc = threadIdx.x & 255;
    const float* xr = x + ((size_t)(b * Nn + (Nn - 1))) * Dd;
    float acc = 0.f;
    for (int d = g * 128; d < (g + 1) * 128; d++)
        acc = fmaf(xr[d], Wout[(size_t)d * Vv + vc], acc);
    if (g) red[g - 1][vc] = acc;
    __syncthreads();
    if (g == 0)
        out[b * Vv + vc] = acc + red[0][vc] + red[1][vc] + red[2][vc] + bout[vc];
}

// ---------------- workspace layout (bytes) — fully disjoint -----------------
static constexpr size_t X_OFF     = 0;          // 8388608  f32 x
static constexpr size_t XN16_OFF  = 8388608;    // 4194304  f16 xn
static constexpr size_t QKV16_OFF = 12582912;   // 12582912 f16 qkv
static constexpr size_t AO16_OFF  = 25165824;   // 4194304  f16 ao | f16 poshl (pre)
static constexpr size_t H1_OFF    = 29360128;   // 16777216 f16 h1 | f32 arg-matrix (pre)
static constexpr size_t AD_OFF    = 46137344;   // 262144
static constexpr size_t AI_OFF    = 46399488;   // 262144
static constexpr size_t SC_OFF    = 46661632;   // 256
static constexpr size_t HV_OFF    = 46661888;   // 2048
static constexpr size_t XX_OFF    = 46663936;   // 8192
static constexpr size_t BQKV_OFF  = 46672128;   // 32768
static constexpr size_t EMB16_OFF = 46704896;   // 262144
static constexpr size_t WBT_OFF   = 46967040;   // 524288
static constexpr size_t WQKVT_OFF = 47491328;   // 6291456  [L][1536][512]
static constexpr size_t WOT_OFF   = 53782784;   // 2097152  [L][512][512]
static constexpr size_t W1T_OFF   = 55879936;   // 8388608  [L][2048][512]
static constexpr size_t W2T_OFF   = 64268544;   // 8388608  [L][512][2048]
static constexpr size_t HP_OFF    = 72657152;   // 65536    hvec partials

extern "C" void kernel_launch(void* const* d_in, const int* in_sizes, int n_in,
                              void* d_out, int out_size, void* d_ws, size_t ws_size,
                              hipStream_t stream) {
    (void)in_sizes; (void)n_in; (void)out_size; (void)ws_size;
    const int*   hashes    = (const int*)  d_in[0];
    const int*   indices   = (const int*)  d_in[1];
    const float* emb       = (const float*)d_in[2];
    const float* hash_proj = (const float*)d_in[3];
    const float* Wb        = (const float*)d_in[4];
    const float* bb        = (const float*)d_in[5];
    const float* log_c     = (const float*)d_in[6];
    const float* pos_t     = (const float*)d_in[7];
    const float* Wq        = (const float*)d_in[8];
    const float* bq        = (const float*)d_in[9];
    const float* Wk        = (const float*)d_in[10];
    const float* bk        = (const float*)d_in[11];
    const float* Wv        = (const float*)d_in[12];
    const float* bv        = (const float*)d_in[13];
    const float* Wo        = (const float*)d_in[14];
    const float* bo        = (const float*)d_in[15];
    const float* W1        = (const float*)d_in[16];
    const float* b1        = (const float*)d_in[17];
    const float* W2        = (const float*)d_in[18];
    const float* b2        = (const float*)d_in[19];
    const float* g1        = (const float*)d_in[20];
    const float* be1       = (const float*)d_in[21];
    const float* g2        = (const float*)d_in[22];
    const float* be2       = (const float*)d_in[23];
    const float* log_tau   = (const float*)d_in[24];
    const float* Wout      = (const float*)d_in[25];
    const float* bout      = (const float*)d_in[26];

    char* ws = (char*)d_ws;
    float* x      = (float*)(ws + X_OFF);
    f16*   xn16   = (f16*)  (ws + XN16_OFF);
    f16*   qkv16  = (f16*)  (ws + QKV16_OFF);
    f16*   ao16   = (f16*)  (ws + AO16_OFF);
    f16*   h1     = (f16*)  (ws + H1_OFF);
    float* adist  = (float*)(ws + AD_OFF);
    int*   aidx   = (int*)  (ws + AI_OFF);
    float* scal   = (float*)(ws + SC_OFF);
    float* hvec   = (float*)(ws + HV_OFF);
    float* xxb    = (float*)(ws + XX_OFF);
    float* bqkv   = (float*)(ws + BQKV_OFF);
    f16*   emb16  = (f16*)  (ws + EMB16_OFF);
    f16*   Wbt    = (f16*)  (ws + WBT_OFF);
    f16*   Wqkvt  = (f16*)  (ws + WQKVT_OFF);
    f16*   Wot    = (f16*)  (ws + WOT_OFF);
    f16*   W1t    = (f16*)  (ws + W1T_OFF);
    f16*   W2t    = (f16*)  (ws + W2T_OFF);
    float* hpart  = (float*)(ws + HP_OFF);
    f16*   poshl  = (f16*)  (ws + AO16_OFF);   // alias, pre-loop only
    float* distb  = (float*)(ws + H1_OFF);     // alias, pre-loop only

    // --- weight prep (runs every call; graph-capture safe) ---
    prep_kernel<<<512, 256, 0, stream>>>(log_c, log_tau, scal, bq, bk, bv, bqkv, emb, emb16);
    hvec_part_kernel<<<32, 256, 0, stream>>>(hash_proj, Wb, hpart);
    hvec_red_kernel<<<2, 256, 0, stream>>>(hpart, hvec);
    trans_kernel<<<dim3(16, 16, 1), 256, 0, stream>>>(Wb, Wbt, 512, 512, 0, 0);
    trans4_kernel<<<dim3(16, 16, 16), 256, 0, stream>>>(Wq, Wk, Wv, Wo, Wqkvt, Wot);
    trans_kernel<<<dim3(64, 16, Ll), 256, 0, stream>>>(W1, W1t, 512, 2048, 1048576, 1048576);
    trans_kernel<<<dim3(16, 64, Ll), 256, 0, stream>>>(W2, W2t, 2048, 512, 1048576, 1048576);

    // --- input projection: x = emb16[indices] @ Wbt^T + hash*hvec + bb (f32 out)
    mgemm<32, 64, true, true, false, false, false><<<dim3(8, 128), 256, 0, stream>>>(
        emb16, Wbt, bb, indices, hashes, hvec, nullptr, x, Mrows, Dd, Dd);

    // --- kNN preprocessing: expmap (hi/lo split) -> MFMA arg -> topk+acosh ---
    expmap_kernel<<<Nn, 256, 0, stream>>>(pos_t, scal, poshl, xxb);
    mdist_kernel<<<528, 256, 0, stream>>>(poshl, xxb, scal, distb);
    topk_kernel<<<Nn, 256, 0, stream>>>(distb, scal, adist, aidx);

    for (int l = 0; l < Ll; l++) {
        ln_kernel<<<Mrows / 4, 256, 0, stream>>>(x, g1 + l * Dd, be1 + l * Dd, xn16);
        // fused QKV: M x 1536, f16 out
        mgemm<64, 128, false, false, false, false, true><<<dim3(12, 64), 256, 0, stream>>>(
            xn16, Wqkvt + (size_t)l * 786432, bqkv + l * 1536,
            nullptr, nullptr, nullptr, nullptr, qkv16, Mrows, 1536, Dd);
        attn_kernel<<<Bb * Nn, 256, 0, stream>>>(qkv16, adist, aidx, scal, l, ao16);
        // Wo + residual, f32 out — TM=32, grid 1024 -> 4 blocks/CU
        mgemm<32, 64, false, false, false, true, false><<<dim3(8, 128), 256, 0, stream>>>(
            ao16, Wot + (size_t)l * 262144, bo + l * Dd,
            nullptr, nullptr, nullptr, x, x, Mrows, Dd, Dd);
        ln_kernel<<<Mrows / 4, 256, 0, stream>>>(x, g2 + l * Dd, be2 + l * Dd, xn16);
        // W1 + GELU, f16 out — R8 winner: 64x128, grid (16,64) -> 3 blocks/CU
        mgemm<64, 128, false, false, true, false, true><<<dim3(16, 64), 256, 0, stream>>>(
            xn16, W1t + (size_t)l * 1048576, b1 + l * 4 * Dd,
            nullptr, nullptr, nullptr, nullptr, h1, Mrows, 4 * Dd, Dd);
        // W2 + residual, f32 out — R8 winner: 32x64, grid (8,128) -> 4 blocks/CU
        mgemm<32, 64, false, false, false, true, false><<<dim3(8, 128), 256, 0, stream>>>(
            h1, W2t + (size_t)l * 1048576, b2 + l * Dd,
            nullptr, nullptr, nullptr, x, x, Mrows, Dd, 4 * Dd);
    }

    out_kernel<<<Bb, 1024, 0, stream>>>(x, Wout, bout, (float*)d_out);
}